// Round 4
// baseline (1026.116 us; speedup 1.0000x reference)
//
#include <hip/hip_runtime.h>
#include <cstdint>
#include <cstddef>

// ---------------- problem constants ----------------
#define NN 8192      // nodes (= LSTM sequence length)
#define FIN 1280
#define HID 320
#define FOUR_H 1280
#define NE 131072
#define NG 1024

// ---- chunked-parallel scan decomposition (MFMA-batched) ----
#define TEAMS 51
#define TPB_TEAM 5
#define B_CH 16
#define CHUNK_L 11
#define BURN 48
#define NSTEPS (BURN + CHUNK_L)   // 59
#define HPAD 344                  // bf16 h row stride (172 dw = 12 mod 32: 2-way max)
#define GPAD 260                  // gates_t row stride (floats)

typedef unsigned short u16;
typedef __attribute__((ext_vector_type(8))) short bf16x8;   // 4 VGPRs
typedef __attribute__((ext_vector_type(4))) float f32x4;

__device__ __forceinline__ float lrelu(float x){ return x > 0.f ? x : 0.01f*x; }
__device__ __forceinline__ u16 f2bf(float f){
  unsigned u = __float_as_uint(f);
  u = (u + 0x7FFFu + ((u >> 16) & 1u)) >> 16;   // RNE
  return (u16)u;
}
__device__ __forceinline__ float bf2f(u16 v){ return __uint_as_float((unsigned)v << 16); }

// ---------------- small prep kernels ----------------
__global__ void k_zero(int* deg){
  int i = blockIdx.x*256 + threadIdx.x;
  if (i < NN) deg[i] = 0;
}

__global__ void k_bias(const float* bi0, const float* bh0, const float* bi1, const float* bh1,
                       float* bs0, float* bs1){
  int i = blockIdx.x*256 + threadIdx.x;
  if (i < 1280) bs0[i] = bi0[i] + bh0[i];
  else if (i < 2560) { int j = i - 1280; bs1[j] = bi1[j] + bh1[j]; }
}

// fp32 -> bf16 convert, zero-padded output columns
__global__ void k_cvt(const float* __restrict__ in, u16* __restrict__ out,
                      int cin, int cout){
  int c = blockIdx.x*256 + threadIdx.x;
  int r = blockIdx.y;
  if (c >= cout) return;
  float v = (c < cin) ? in[(size_t)r*cin + c] : 0.f;
  out[(size_t)r*cout + c] = f2bf(v);
}

// bf16 -> bf16 leaky-relu (GCN input from LSTM output)
__global__ void k_lrelu_bf(const u16* __restrict__ in, u16* __restrict__ out){
  int i = blockIdx.x*256 + threadIdx.x;   // grid covers NN*HID
  out[i] = f2bf(lrelu(bf2f(in[i])));
}

// W [K,N] fp32 -> WT [n][k] bf16, zero padded to [NR][KC]
__global__ void k_wT(const float* __restrict__ W, u16* __restrict__ WT,
                     int K, int Nn, int KC){
  int n = blockIdx.x;
  int k = blockIdx.y*256 + threadIdx.x;
  if (k >= KC) return;
  float v = (n < Nn && k < K) ? W[(size_t)k*Nn + n] : 0.f;
  WT[(size_t)n*KC + k] = f2bf(v);
}

// ------- bf16 MFMA GEMM: C[M,N] = A[M,K] * B[N,K]^T + bias, bf16 out -------
// 128x64 tile, 256 thr (4 waves); wave w: rows [w*32,w*32+32) x 64 cols.
__global__ __launch_bounds__(256) void gemm_bt(
    const u16* __restrict__ A, int lda,
    const u16* __restrict__ B, int ldb,
    u16* __restrict__ C, int ldc, int Nn, int kIters,
    const float* __restrict__ bias)
{
  __shared__ __align__(16) u16 As[128][40];
  __shared__ __align__(16) u16 Bs[64][40];
  int t = threadIdx.x; int wv = t >> 6; int ln = t & 63;
  int m0 = blockIdx.x*128, n0 = blockIdx.y*64;
  f32x4 acc[2][4];
  #pragma unroll
  for (int a = 0; a < 2; ++a)
    #pragma unroll
    for (int j = 0; j < 4; ++j) acc[a][j] = (f32x4){0,0,0,0};
  int sr = t >> 2, sc = (t & 3) * 8;
  const u16* Ap0 = A + (size_t)(m0+sr)*lda + sc;
  const u16* Ap1 = A + (size_t)(m0+64+sr)*lda + sc;
  const u16* Bp  = B + (size_t)(n0+sr)*ldb + sc;
  int fr = ln & 15, quad = ln >> 4;
  for (int kt = 0; kt < kIters; ++kt){
    uint4 a0 = *(const uint4*)(Ap0 + kt*32);
    uint4 a1 = *(const uint4*)(Ap1 + kt*32);
    uint4 bv = *(const uint4*)(Bp  + kt*32);
    *(uint4*)(&As[sr][sc])    = a0;
    *(uint4*)(&As[64+sr][sc]) = a1;
    *(uint4*)(&Bs[sr][sc])    = bv;
    __syncthreads();
    bf16x8 afA = *(const bf16x8*)(&As[wv*32 +      fr][quad*8]);
    bf16x8 afB = *(const bf16x8*)(&As[wv*32 + 16 + fr][quad*8]);
    #pragma unroll
    for (int j = 0; j < 4; ++j){
      bf16x8 bf = *(const bf16x8*)(&Bs[j*16 + fr][quad*8]);
      acc[0][j] = __builtin_amdgcn_mfma_f32_16x16x32_bf16(afA, bf, acc[0][j], 0,0,0);
      acc[1][j] = __builtin_amdgcn_mfma_f32_16x16x32_bf16(afB, bf, acc[1][j], 0,0,0);
    }
    __syncthreads();
  }
  #pragma unroll
  for (int a = 0; a < 2; ++a){
    int row0 = m0 + wv*32 + a*16 + quad*4;
    #pragma unroll
    for (int nt = 0; nt < 4; ++nt){
      int col = n0 + nt*16 + fr;
      if (col < Nn){
        float bb = bias ? bias[col] : 0.f;
        #pragma unroll
        for (int i = 0; i < 4; ++i)
          C[(size_t)(row0+i)*ldc + col] = f2bf(acc[a][nt][i] + bb);
      }
    }
  }
}

// ---------------- MFMA-batched chunk-parallel LSTM scan ----------------
// Tagged-publish sync (R4): each lane's h-pair goes out as ONE relaxed
// agent-scope 8B atomic {tag=sl+1 | packed bf16x2}. No flags, no pre-drain:
// remote poll reads ARE the data pull (2 LLC trips vs R3's 4). Parity
// double-buffer makes slot reuse architecturally race-free (overwrite of
// slot p requires the overwriter to have consumed the victim's NEXT step).
// Poison 0xAA never matches a tag (tags are 1..59), so no init needed.
__global__ __launch_bounds__(512, 2) void lstm_scan(
    const u16* __restrict__ gxb, const u16* __restrict__ Whh_bf,
    u16* __restrict__ hout, unsigned long long* pub)
{
  int b = blockIdx.x;
  int team = b / TPB_TEAM, blk = b % TPB_TEAM;
  int t = threadIdx.x;
  int w = t >> 6, lane = t & 63;
  int fr = lane & 15, quad = lane >> 4;

  // register-resident bf16 B-fragments of W_hh (2 N-tiles x 10 K-frags)
  bf16x8 wf0[10], wf1[10];
  {
    int n0l = w*32 + fr;
    int n1l = w*32 + 16 + fr;
    int g0 = n0l >> 6, u0 = n0l & 63;
    int g1 = n1l >> 6, u1 = n1l & 63;
    const u16* wp0 = Whh_bf + (size_t)(g0*320 + blk*64 + u0)*320 + quad*8;
    const u16* wp1 = Whh_bf + (size_t)(g1*320 + blk*64 + u1)*320 + quad*8;
    #pragma unroll
    for (int kt = 0; kt < 10; ++kt){
      wf0[kt] = *(const bf16x8*)(wp0 + kt*32);
      wf1[kt] = *(const bf16x8*)(wp1 + kt*32);
    }
  }

  __shared__ __align__(16) u16 h_bf[2][B_CH][HPAD];     // bf16 h, A-frag layout
  __shared__ __align__(16) float gates_t[B_CH][GPAD];   // [chunk][n_local]
  for (int i = t; i < 2*B_CH*HPAD; i += 512) ((u16*)h_bf)[i] = 0;

  int chunk = t >> 5;
  int ul = t & 31;
  int cid = team*B_CH + chunk;
  int cstart = cid * CHUNK_L;
  int cend = min(NN, cstart + CHUNK_L);
  float c0 = 0.f, c1 = 0.f;
  unsigned long long* pub_t = pub + (size_t)team * (2*TPB_TEAM*512);

  // one-step-ahead gx prefetch (bf16): latency hides under the sync phase
  float gxn[8];
  {
    int s = cstart - BURN;
    bool sv = (s >= 0) && (s < NN);
    #pragma unroll
    for (int r = 0; r < 2; ++r)
      #pragma unroll
      for (int g = 0; g < 4; ++g)
        gxn[r*4+g] = sv ? bf2f(gxb[(size_t)s*FOUR_H + g*320 + blk*64 + ul + 32*r]) : 0.f;
  }
  __syncthreads();

  for (int sl = 0; sl < NSTEPS; ++sl){
    int par = sl & 1;
    int s = cstart - BURN + sl;
    float gxv[8];
    #pragma unroll
    for (int i = 0; i < 8; ++i) gxv[i] = gxn[i];
    {
      int sn = s + 1;
      bool sv = (sl+1 < NSTEPS) && (sn >= 0) && (sn < NN);
      #pragma unroll
      for (int r = 0; r < 2; ++r)
        #pragma unroll
        for (int g = 0; g < 4; ++g)
          gxn[r*4+g] = sv ? bf2f(gxb[(size_t)sn*FOUR_H + g*320 + blk*64 + ul + 32*r]) : 0.f;
    }

    // batched matvec: gates[16 chunks][256 rows] = h x W^T
    f32x4 acc0 = {0,0,0,0}, acc1 = {0,0,0,0};
    #pragma unroll
    for (int kt = 0; kt < 10; ++kt){
      bf16x8 a = *(const bf16x8*)(&h_bf[par][fr][kt*32 + quad*8]);
      acc0 = __builtin_amdgcn_mfma_f32_16x16x32_bf16(a, wf0[kt], acc0, 0, 0, 0);
      acc1 = __builtin_amdgcn_mfma_f32_16x16x32_bf16(a, wf1[kt], acc1, 0, 0, 0);
    }
    #pragma unroll
    for (int i = 0; i < 4; ++i){
      gates_t[quad*4+i][w*32 +      fr] = acc0[i];
      gates_t[quad*4+i][w*32 + 16 + fr] = acc1[i];
    }
    __syncthreads();

    float hv0, hv1;
    {
      int u = ul;
      float gi = gates_t[chunk][      u] + gxv[0];
      float gf = gates_t[chunk][ 64 + u] + gxv[1];
      float gg = gates_t[chunk][128 + u] + gxv[2];
      float go = gates_t[chunk][192 + u] + gxv[3];
      float si = 1.f/(1.f + __expf(-gi));
      float sf = 1.f/(1.f + __expf(-gf));
      float tg = 1.f - 2.f/(1.f + __expf(2.f*gg));
      c0 = sf*c0 + si*tg;
      float th = 1.f - 2.f/(1.f + __expf(2.f*c0));
      hv0 = (1.f/(1.f + __expf(-go))) * th;
    }
    {
      int u = ul + 32;
      float gi = gates_t[chunk][      u] + gxv[4];
      float gf = gates_t[chunk][ 64 + u] + gxv[5];
      float gg = gates_t[chunk][128 + u] + gxv[6];
      float go = gates_t[chunk][192 + u] + gxv[7];
      float si = 1.f/(1.f + __expf(-gi));
      float sf = 1.f/(1.f + __expf(-gf));
      float tg = 1.f - 2.f/(1.f + __expf(2.f*gg));
      c1 = sf*c1 + si*tg;
      float th = 1.f - 2.f/(1.f + __expf(2.f*c1));
      hv1 = (1.f/(1.f + __expf(-go))) * th;
    }
    u16 hb0 = f2bf(hv0), hb1 = f2bf(hv1);
    // own slice -> local LDS for next step
    h_bf[par^1][chunk][blk*64 + ul     ] = hb0;
    h_bf[par^1][chunk][blk*64 + ul + 32] = hb1;
    // tagged publish: one 8B atomic carries data + validity
    {
      unsigned pk32 = (unsigned)hb0 | ((unsigned)hb1 << 16);
      unsigned long long pk = (unsigned long long)pk32
                            | ((unsigned long long)(unsigned)(sl+1) << 32);
      __hip_atomic_store(&pub_t[par*(TPB_TEAM*512) + blk*512 + t], pk,
                         __ATOMIC_RELAXED, __HIP_MEMORY_SCOPE_AGENT);
    }
    if (s >= cstart && s < cend){
      hout[(size_t)s*HID + blk*64 + ul     ] = hb0;
      hout[(size_t)s*HID + blk*64 + ul + 32] = hb1;
    }
    // poll remote tagged slots (read IS the pull)
    #pragma unroll
    for (int j = 0; j < 4; ++j){
      int rb = j + (j >= blk);
      const unsigned long long* ap = &pub_t[par*(TPB_TEAM*512) + rb*512 + t];
      unsigned long long v = __hip_atomic_load(ap, __ATOMIC_RELAXED, __HIP_MEMORY_SCOPE_AGENT);
      while ((unsigned)(v >> 32) != (unsigned)(sl+1)){
        __builtin_amdgcn_s_sleep(1);
        v = __hip_atomic_load(ap, __ATOMIC_RELAXED, __HIP_MEMORY_SCOPE_AGENT);
      }
      unsigned pk2 = (unsigned)v;
      h_bf[par^1][chunk][rb*64 + ul     ] = (u16)(pk2 & 0xFFFFu);
      h_bf[par^1][chunk][rb*64 + ul + 32] = (u16)(pk2 >> 16);
    }
    __syncthreads();
  }
}

// ---------------- GCN: CSR build (counting sort by dst) + gather ----------------
__global__ void k_hist(const int* __restrict__ ei, int* deg){
  int e = blockIdx.x*256 + threadIdx.x;
  if (e < NE) atomicAdd(&deg[ei[NE + e]], 1);
}

__global__ void k_offsets(const int* __restrict__ deg, int* off, int* cursor){
  __shared__ int sdata[1024];
  int t = threadIdx.x;
  int loc[8]; int s = 0;
  #pragma unroll
  for (int j = 0; j < 8; j++){ loc[j] = deg[t*8 + j]; s += loc[j]; }
  sdata[t] = s; __syncthreads();
  for (int d = 1; d < 1024; d <<= 1){
    int add = (t >= d) ? sdata[t-d] : 0;
    __syncthreads();
    sdata[t] += add;
    __syncthreads();
  }
  int run = sdata[t] - s;
  #pragma unroll
  for (int j = 0; j < 8; j++){ off[t*8+j] = run; cursor[t*8+j] = run; run += loc[j]; }
  if (t == 1023) off[NN] = run;
}

__global__ void k_scatter(const int* __restrict__ ei, const float* __restrict__ ew,
                          int* cursor, int* esrc, float* ews){
  int e = blockIdx.x*256 + threadIdx.x;
  if (e < NE){
    int d = ei[NE + e];
    int p = atomicAdd(&cursor[d], 1);
    esrc[p] = ei[e];
    ews[p] = ew[e];
  }
}

// one wave per dst node; XW is packed-bf16 (F2 u32/row). Output either
// packed-bf16 (ld2 u32/row, zero-padded) or fp32 (layer 4).
__global__ void k_gather(const u16* __restrict__ XWb, int F2,
    const int* __restrict__ off, const int* __restrict__ esrc, const float* __restrict__ ews,
    const float* __restrict__ bias, u16* outb, float* outf, int ld2, int Fo, int lrFlag)
{
  int node = blockIdx.x*4 + (threadIdx.x >> 6);
  int lane = threadIdx.x & 63;
  const unsigned* XW2 = (const unsigned*)XWb;
  float2 acc[3];
  #pragma unroll
  for (int j = 0; j < 3; ++j) acc[j] = (float2){0.f, 0.f};
  int e0 = off[node], e1 = off[node+1];
  for (int e = e0; e < e1; ++e){
    int sN = esrc[e]; float we = ews[e];
    const unsigned* xr = XW2 + (size_t)sN*F2;
    #pragma unroll
    for (int j = 0; j < 3; ++j){
      int i = j*64 + lane;
      if (i < F2){
        unsigned u = xr[i];
        acc[j].x += we * bf2f((u16)(u & 0xFFFFu));
        acc[j].y += we * bf2f((u16)(u >> 16));
      }
    }
  }
  #pragma unroll
  for (int j = 0; j < 3; ++j){
    int i = j*64 + lane;
    if (i < F2){
      float v0 = acc[j].x + bias[2*i];
      float v1 = acc[j].y + bias[2*i+1];
      if (lrFlag){ v0 = lrelu(v0); v1 = lrelu(v1); }
      if (outb){
        unsigned pk = (unsigned)f2bf(v0) | ((unsigned)f2bf(v1) << 16);
        ((unsigned*)outb)[(size_t)node*ld2 + i] = pk;
      } else {
        outf[(size_t)node*Fo + 2*i    ] = v0;
        outf[(size_t)node*Fo + 2*i + 1] = v1;
      }
    }
  }
  if (outb){
    for (int i = F2 + lane; i < ld2; i += 64)
      ((unsigned*)outb)[(size_t)node*ld2 + i] = 0u;
  }
}

// ---------------- BN stats + fused BN/pool/FC ----------------
__global__ void k_bnstats(const float* __restrict__ conv4, float* mu, float* iv){
  int f = blockIdx.x, t = threadIdx.x;
  float s = 0, ss = 0;
  for (int i = t; i < NN; i += 256){ float v = conv4[(size_t)i*50 + f]; s += v; ss += v*v; }
  __shared__ float S[256], SS[256];
  S[t] = s; SS[t] = ss; __syncthreads();
  for (int d = 128; d > 0; d >>= 1){ if (t < d){ S[t] += S[t+d]; SS[t] += SS[t+d]; } __syncthreads(); }
  if (t == 0){
    float m = S[0] / (float)NN;
    float var = SS[0] / (float)NN - m*m;
    mu[f] = m; iv[f] = rsqrtf(var + 1e-5f);
  }
}

__global__ void k_final(const float* __restrict__ conv4, const float* __restrict__ mu,
    const float* __restrict__ iv, const float* __restrict__ gamma, const float* __restrict__ beta,
    const float* __restrict__ f1W, const float* __restrict__ f1b,
    const float* __restrict__ f2W, const float* __restrict__ f2b,
    const float* __restrict__ f3W, const float* __restrict__ f3b, float* __restrict__ out)
{
  int g = blockIdx.x, t = threadIdx.x;
  __shared__ float pl[50]; __shared__ float o1[30]; __shared__ float o2[20];
  if (t < 50){
    float mf = mu[t], ivf = iv[t], ga = gamma[t], be = beta[t];
    float s = 0;
    for (int i = 0; i < 8; i++){
      float v = conv4[(size_t)(g*8+i)*50 + t];
      v = ga*(v - mf)*ivf + be;
      s += lrelu(v);
    }
    pl[t] = s;
  }
  __syncthreads();
  if (t < 30){ float a = f1b[t]; for (int f = 0; f < 50; f++) a += pl[f]*f1W[f*30+t]; o1[t] = lrelu(a); }
  __syncthreads();
  if (t < 20){ float a = f2b[t]; for (int j = 0; j < 30; j++) a += o1[j]*f2W[j*20+t]; o2[t] = lrelu(a); }
  __syncthreads();
  if (t < 2){  float a = f3b[t]; for (int j = 0; j < 20; j++) a += o2[j]*f3W[j*2+t]; out[g*2+t] = lrelu(a); }
}

// ---------------- host ----------------
extern "C" void kernel_launch(void* const* d_in, const int* in_sizes, int n_in,
                              void* d_out, int out_size, void* d_ws, size_t ws_size,
                              hipStream_t stream) {
  const float* x    = (const float*)d_in[0];
  const int*   ei   = (const int*)  d_in[1];
  const float* ew   = (const float*)d_in[2];
  const float* Wih0 = (const float*)d_in[4];
  const float* Whh0 = (const float*)d_in[5];
  const float* bi0  = (const float*)d_in[6];
  const float* bh0  = (const float*)d_in[7];
  const float* Wih1 = (const float*)d_in[8];
  const float* Whh1 = (const float*)d_in[9];
  const float* bi1  = (const float*)d_in[10];
  const float* bh1  = (const float*)d_in[11];
  const float* Wg1  = (const float*)d_in[12];
  const float* bg1  = (const float*)d_in[13];
  const float* Wg2  = (const float*)d_in[14];
  const float* bg2  = (const float*)d_in[15];
  const float* Wg3  = (const float*)d_in[16];
  const float* bg3  = (const float*)d_in[17];
  const float* Wg4  = (const float*)d_in[18];
  const float* bg4  = (const float*)d_in[19];
  const float* gam  = (const float*)d_in[20];
  const float* bet  = (const float*)d_in[21];
  const float* f1W  = (const float*)d_in[22];
  const float* f1b  = (const float*)d_in[23];
  const float* f2W  = (const float*)d_in[24];
  const float* f2b  = (const float*)d_in[25];
  const float* f3W  = (const float*)d_in[26];
  const float* f3b  = (const float*)d_in[27];

  char* ws = (char*)d_ws;
  size_t o = 0;
  auto alloc = [&](size_t bytes)->char*{ char* p = ws + o; o += (bytes + 255) & ~(size_t)255; return p; };
  u16*   gxb   = (u16*)  alloc((size_t)NN*FOUR_H*2);   // bf16 gx (reused layer0/1)
  u16*   h0b   = (u16*)  alloc((size_t)NN*HID*2);      // scan0 out
  u16*   h1b   = (u16*)  alloc((size_t)NN*HID*2);      // scan1 out
  u16*   actA  = (u16*)  alloc((size_t)NN*FIN*2);      // x bf16
  u16*   actL  = (u16*)  alloc((size_t)NN*HID*2);      // lrelu(h1)
  u16*   g1o   = (u16*)  alloc((size_t)NN*320*2);
  u16*   g2o   = (u16*)  alloc((size_t)NN*192*2);
  u16*   g3o   = (u16*)  alloc((size_t)NN*96*2);
  u16*   XW    = (u16*)  alloc((size_t)NN*320*2);      // per-layer transform out
  float* conv4 = (float*)alloc((size_t)NN*50*4);
  u16*   Wih0b = (u16*)  alloc((size_t)1280*1280*2);
  u16*   Wih1b = (u16*)  alloc((size_t)1280*320*2);
  u16*   Whh0b = (u16*)  alloc((size_t)1280*320*2);
  u16*   Whh1b = (u16*)  alloc((size_t)1280*320*2);
  u16*   W1T   = (u16*)  alloc((size_t)320*320*2);
  u16*   W2T   = (u16*)  alloc((size_t)192*320*2);
  u16*   W3T   = (u16*)  alloc((size_t)128*192*2);
  u16*   W4T   = (u16*)  alloc((size_t)64*96*2);
  float* bs0   = (float*)alloc(1280*4);
  float* bs1   = (float*)alloc(1280*4);
  float* mu    = (float*)alloc(256);
  float* iv    = (float*)alloc(256);
  int*   deg   = (int*)  alloc(NN*4);
  int*   off   = (int*)  alloc((NN+1)*4);
  int*   cursor= (int*)  alloc(NN*4);
  int*   esrc  = (int*)  alloc((size_t)NE*4);
  float* ews   = (float*)alloc((size_t)NE*4);
  unsigned long long* pub0 = (unsigned long long*)alloc((size_t)TEAMS*2*TPB_TEAM*512*8);
  unsigned long long* pub1 = (unsigned long long*)alloc((size_t)TEAMS*2*TPB_TEAM*512*8);
  (void)ws_size; (void)in_sizes; (void)n_in; (void)out_size;

  // prep
  k_zero<<<32, 256, 0, stream>>>(deg);
  k_bias<<<10, 256, 0, stream>>>(bi0, bh0, bi1, bh1, bs0, bs1);
  k_cvt<<<dim3(5, NN),   256, 0, stream>>>(x,    actA,  1280, 1280);
  k_cvt<<<dim3(5, 1280), 256, 0, stream>>>(Wih0, Wih0b, 1280, 1280);
  k_cvt<<<dim3(2, 1280), 256, 0, stream>>>(Wih1, Wih1b, 320,  320);
  k_cvt<<<dim3(2, 1280), 256, 0, stream>>>(Whh0, Whh0b, 320,  320);
  k_cvt<<<dim3(2, 1280), 256, 0, stream>>>(Whh1, Whh1b, 320,  320);
  k_wT<<<dim3(320, 2), 256, 0, stream>>>(Wg1, W1T, 320, 320, 320);
  k_wT<<<dim3(192, 2), 256, 0, stream>>>(Wg2, W2T, 320, 180, 320);
  k_wT<<<dim3(128, 1), 256, 0, stream>>>(Wg3, W3T, 180, 90, 192);
  k_wT<<<dim3(64, 1),  256, 0, stream>>>(Wg4, W4T, 90, 50, 96);
  // CSR build
  k_hist<<<512, 256, 0, stream>>>(ei, deg);
  k_offsets<<<1, 1024, 0, stream>>>(deg, off, cursor);
  k_scatter<<<512, 256, 0, stream>>>(ei, ew, cursor, esrc, ews);

  // LSTM layer 0
  gemm_bt<<<dim3(64, 20), 256, 0, stream>>>(actA, 1280, Wih0b, 1280, gxb, 1280, 1280, 40, bs0);
  {
    const u16* a0 = gxb; const u16* a1 = Whh0b; u16* a2 = h0b; unsigned long long* a3 = pub0;
    void* kargs[4] = {&a0, &a1, &a2, &a3};
    if (hipLaunchCooperativeKernel((const void*)lstm_scan, dim3(TEAMS*TPB_TEAM), dim3(512),
                                   kargs, 0, stream) != hipSuccess)
      lstm_scan<<<dim3(TEAMS*TPB_TEAM), 512, 0, stream>>>(a0, a1, a2, a3);
  }
  // LSTM layer 1 (consumes h0b bf16 directly)
  gemm_bt<<<dim3(64, 20), 256, 0, stream>>>(h0b, 320, Wih1b, 320, gxb, 1280, 1280, 10, bs1);
  {
    const u16* a0 = gxb; const u16* a1 = Whh1b; u16* a2 = h1b; unsigned long long* a3 = pub1;
    void* kargs[4] = {&a0, &a1, &a2, &a3};
    if (hipLaunchCooperativeKernel((const void*)lstm_scan, dim3(TEAMS*TPB_TEAM), dim3(512),
                                   kargs, 0, stream) != hipSuccess)
      lstm_scan<<<dim3(TEAMS*TPB_TEAM), 512, 0, stream>>>(a0, a1, a2, a3);
  }
  k_lrelu_bf<<<NN*HID/256, 256, 0, stream>>>(h1b, actL);

  // GCN stack (XW bf16-packed; gathers read u32 pairs)
  gemm_bt<<<dim3(64, 5), 256, 0, stream>>>(actL, 320, W1T, 320, XW, 320, 320, 10, nullptr);
  k_gather<<<2048, 256, 0, stream>>>(XW, 160, off, esrc, ews, bg1, g1o, nullptr, 160, 320, 1);
  gemm_bt<<<dim3(64, 3), 256, 0, stream>>>(g1o, 320, W2T, 320, XW, 180, 180, 10, nullptr);
  k_gather<<<2048, 256, 0, stream>>>(XW, 90, off, esrc, ews, bg2, g2o, nullptr, 96, 180, 1);
  gemm_bt<<<dim3(64, 2), 256, 0, stream>>>(g2o, 192, W3T, 192, XW, 90, 90, 6, nullptr);
  k_gather<<<2048, 256, 0, stream>>>(XW, 45, off, esrc, ews, bg3, g3o, nullptr, 48, 90, 1);
  gemm_bt<<<dim3(64, 1), 256, 0, stream>>>(g3o, 96, W4T, 96, XW, 50, 50, 3, nullptr);
  k_gather<<<2048, 256, 0, stream>>>(XW, 25, off, esrc, ews, bg4, nullptr, conv4, 0, 50, 0);

  // BN + pool + FC head
  k_bnstats<<<50, 256, 0, stream>>>(conv4, mu, iv);
  k_final<<<NG, 64, 0, stream>>>(conv4, mu, iv, gam, bet, f1W, f1b, f2W, f2b, f3W, f3b,
                                 (float*)d_out);
}

// Round 5
// 890.941 us; speedup vs baseline: 1.1517x; 1.1517x over previous
//
#include <hip/hip_runtime.h>
#include <cstdint>
#include <cstddef>

// ---------------- problem constants ----------------
#define NN 8192      // nodes (= LSTM sequence length)
#define FIN 1280
#define HID 320
#define FOUR_H 1280
#define NE 131072
#define NG 1024

// ---- chunked-parallel scan decomposition (MFMA-batched) ----
#define TEAMS 51
#define TPB_TEAM 5
#define B_CH 16
#define CHUNK_L 11
#define BURN 40       // R5: 48->40; 4-sigma truncation ~1e-6 << bf16 noise 6e-4
#define NSTEPS (BURN + CHUNK_L)   // 51
#define HPAD 344                  // bf16 h row stride
#define GPAD 260                  // gates_t row stride (floats)

typedef unsigned short u16;
typedef unsigned long long u64;
typedef __attribute__((ext_vector_type(8))) short bf16x8;   // 4 VGPRs
typedef __attribute__((ext_vector_type(4))) float f32x4;

__device__ __forceinline__ float lrelu(float x){ return x > 0.f ? x : 0.01f*x; }
__device__ __forceinline__ u16 f2bf(float f){
  unsigned u = __float_as_uint(f);
  u = (u + 0x7FFFu + ((u >> 16) & 1u)) >> 16;   // RNE
  return (u16)u;
}
__device__ __forceinline__ float bf2f(u16 v){ return __uint_as_float((unsigned)v << 16); }

// ---------------- small prep kernels ----------------
__global__ void k_zero(int* deg){
  int i = blockIdx.x*256 + threadIdx.x;
  if (i < NN) deg[i] = 0;
}

__global__ void k_bias(const float* bi0, const float* bh0, const float* bi1, const float* bh1,
                       float* bs0, float* bs1){
  int i = blockIdx.x*256 + threadIdx.x;
  if (i < 1280) bs0[i] = bi0[i] + bh0[i];
  else if (i < 2560) { int j = i - 1280; bs1[j] = bi1[j] + bh1[j]; }
}

// fp32 -> bf16 convert, zero-padded output columns
__global__ void k_cvt(const float* __restrict__ in, u16* __restrict__ out,
                      int cin, int cout){
  int c = blockIdx.x*256 + threadIdx.x;
  int r = blockIdx.y;
  if (c >= cout) return;
  float v = (c < cin) ? in[(size_t)r*cin + c] : 0.f;
  out[(size_t)r*cout + c] = f2bf(v);
}

// bf16 -> bf16 leaky-relu
__global__ void k_lrelu_bf(const u16* __restrict__ in, u16* __restrict__ out){
  int i = blockIdx.x*256 + threadIdx.x;
  out[i] = f2bf(lrelu(bf2f(in[i])));
}

// W [K,N] fp32 -> WT [n][k] bf16, zero padded to [NR][KC]
__global__ void k_wT(const float* __restrict__ W, u16* __restrict__ WT,
                     int K, int Nn, int KC){
  int n = blockIdx.x;
  int k = blockIdx.y*256 + threadIdx.x;
  if (k >= KC) return;
  float v = (n < Nn && k < K) ? W[(size_t)k*Nn + n] : 0.f;
  WT[(size_t)n*KC + k] = f2bf(v);
}

// ------- bf16 MFMA GEMM: C[M,N] = A[M,K] * B[N,K]^T + bias, bf16 out -------
__global__ __launch_bounds__(256) void gemm_bt(
    const u16* __restrict__ A, int lda,
    const u16* __restrict__ B, int ldb,
    u16* __restrict__ C, int ldc, int Nn, int kIters,
    const float* __restrict__ bias)
{
  __shared__ __align__(16) u16 As[128][40];
  __shared__ __align__(16) u16 Bs[64][40];
  int t = threadIdx.x; int wv = t >> 6; int ln = t & 63;
  int m0 = blockIdx.x*128, n0 = blockIdx.y*64;
  f32x4 acc[2][4];
  #pragma unroll
  for (int a = 0; a < 2; ++a)
    #pragma unroll
    for (int j = 0; j < 4; ++j) acc[a][j] = (f32x4){0,0,0,0};
  int sr = t >> 2, sc = (t & 3) * 8;
  const u16* Ap0 = A + (size_t)(m0+sr)*lda + sc;
  const u16* Ap1 = A + (size_t)(m0+64+sr)*lda + sc;
  const u16* Bp  = B + (size_t)(n0+sr)*ldb + sc;
  int fr = ln & 15, quad = ln >> 4;
  for (int kt = 0; kt < kIters; ++kt){
    uint4 a0 = *(const uint4*)(Ap0 + kt*32);
    uint4 a1 = *(const uint4*)(Ap1 + kt*32);
    uint4 bv = *(const uint4*)(Bp  + kt*32);
    *(uint4*)(&As[sr][sc])    = a0;
    *(uint4*)(&As[64+sr][sc]) = a1;
    *(uint4*)(&Bs[sr][sc])    = bv;
    __syncthreads();
    bf16x8 afA = *(const bf16x8*)(&As[wv*32 +      fr][quad*8]);
    bf16x8 afB = *(const bf16x8*)(&As[wv*32 + 16 + fr][quad*8]);
    #pragma unroll
    for (int j = 0; j < 4; ++j){
      bf16x8 bf = *(const bf16x8*)(&Bs[j*16 + fr][quad*8]);
      acc[0][j] = __builtin_amdgcn_mfma_f32_16x16x32_bf16(afA, bf, acc[0][j], 0,0,0);
      acc[1][j] = __builtin_amdgcn_mfma_f32_16x16x32_bf16(afB, bf, acc[1][j], 0,0,0);
    }
    __syncthreads();
  }
  #pragma unroll
  for (int a = 0; a < 2; ++a){
    int row0 = m0 + wv*32 + a*16 + quad*4;
    #pragma unroll
    for (int nt = 0; nt < 4; ++nt){
      int col = n0 + nt*16 + fr;
      if (col < Nn){
        float bb = bias ? bias[col] : 0.f;
        #pragma unroll
        for (int i = 0; i < 4; ++i)
          C[(size_t)(row0+i)*ldc + col] = f2bf(acc[a][nt][i] + bb);
      }
    }
  }
}

// ---------------- MFMA-batched chunk-parallel LSTM scan ----------------
// Tagged publish (R4) + PARALLEL wait-all poll (R5): all 4 remote tagged
// loads issue back-to-back each retry round (one LLC latency per round,
// not per slot — R4 serialized them and regressed 213->263us).
__global__ __launch_bounds__(512, 2) void lstm_scan(
    const u16* __restrict__ gxb, const u16* __restrict__ Whh_bf,
    u16* __restrict__ hout, u64* pub)
{
  int b = blockIdx.x;
  int team = b / TPB_TEAM, blk = b % TPB_TEAM;
  int t = threadIdx.x;
  int w = t >> 6, lane = t & 63;
  int fr = lane & 15, quad = lane >> 4;

  // register-resident bf16 B-fragments of W_hh (2 N-tiles x 10 K-frags)
  bf16x8 wf0[10], wf1[10];
  {
    int n0l = w*32 + fr;
    int n1l = w*32 + 16 + fr;
    int g0 = n0l >> 6, u0 = n0l & 63;
    int g1 = n1l >> 6, u1 = n1l & 63;
    const u16* wp0 = Whh_bf + (size_t)(g0*320 + blk*64 + u0)*320 + quad*8;
    const u16* wp1 = Whh_bf + (size_t)(g1*320 + blk*64 + u1)*320 + quad*8;
    #pragma unroll
    for (int kt = 0; kt < 10; ++kt){
      wf0[kt] = *(const bf16x8*)(wp0 + kt*32);
      wf1[kt] = *(const bf16x8*)(wp1 + kt*32);
    }
  }

  __shared__ __align__(16) u16 h_bf[2][B_CH][HPAD];     // bf16 h, A-frag layout
  __shared__ __align__(16) float gates_t[B_CH][GPAD];   // [chunk][n_local]
  for (int i = t; i < 2*B_CH*HPAD; i += 512) ((u16*)h_bf)[i] = 0;

  int chunk = t >> 5;
  int ul = t & 31;
  int cid = team*B_CH + chunk;
  int cstart = cid * CHUNK_L;
  int cend = min(NN, cstart + CHUNK_L);
  float c0 = 0.f, c1 = 0.f;
  u64* pub_t = pub + (size_t)team * (2*TPB_TEAM*512);
  // the 4 remote slot addresses for this thread (fixed across steps, mod parity)
  const u64* rp[4];
  #pragma unroll
  for (int j = 0; j < 4; ++j){
    int rb = j + (j >= blk);
    rp[j] = &pub_t[rb*512 + t];
  }

  // one-step-ahead gx prefetch (bf16)
  float gxn[8];
  {
    int s = cstart - BURN;
    bool sv = (s >= 0) && (s < NN);
    #pragma unroll
    for (int r = 0; r < 2; ++r)
      #pragma unroll
      for (int g = 0; g < 4; ++g)
        gxn[r*4+g] = sv ? bf2f(gxb[(size_t)s*FOUR_H + g*320 + blk*64 + ul + 32*r]) : 0.f;
  }
  __syncthreads();

  for (int sl = 0; sl < NSTEPS; ++sl){
    int par = sl & 1;
    int s = cstart - BURN + sl;
    float gxv[8];
    #pragma unroll
    for (int i = 0; i < 8; ++i) gxv[i] = gxn[i];
    {
      int sn = s + 1;
      bool sv = (sl+1 < NSTEPS) && (sn >= 0) && (sn < NN);
      #pragma unroll
      for (int r = 0; r < 2; ++r)
        #pragma unroll
        for (int g = 0; g < 4; ++g)
          gxn[r*4+g] = sv ? bf2f(gxb[(size_t)sn*FOUR_H + g*320 + blk*64 + ul + 32*r]) : 0.f;
    }

    // batched matvec: gates[16 chunks][256 rows] = h x W^T
    f32x4 acc0 = {0,0,0,0}, acc1 = {0,0,0,0};
    #pragma unroll
    for (int kt = 0; kt < 10; ++kt){
      bf16x8 a = *(const bf16x8*)(&h_bf[par][fr][kt*32 + quad*8]);
      acc0 = __builtin_amdgcn_mfma_f32_16x16x32_bf16(a, wf0[kt], acc0, 0, 0, 0);
      acc1 = __builtin_amdgcn_mfma_f32_16x16x32_bf16(a, wf1[kt], acc1, 0, 0, 0);
    }
    #pragma unroll
    for (int i = 0; i < 4; ++i){
      gates_t[quad*4+i][w*32 +      fr] = acc0[i];
      gates_t[quad*4+i][w*32 + 16 + fr] = acc1[i];
    }
    __syncthreads();

    float hv0, hv1;
    {
      int u = ul;
      float gi = gates_t[chunk][      u] + gxv[0];
      float gf = gates_t[chunk][ 64 + u] + gxv[1];
      float gg = gates_t[chunk][128 + u] + gxv[2];
      float go = gates_t[chunk][192 + u] + gxv[3];
      float si = 1.f/(1.f + __expf(-gi));
      float sf = 1.f/(1.f + __expf(-gf));
      float tg = 1.f - 2.f/(1.f + __expf(2.f*gg));
      c0 = sf*c0 + si*tg;
      float th = 1.f - 2.f/(1.f + __expf(2.f*c0));
      hv0 = (1.f/(1.f + __expf(-go))) * th;
    }
    {
      int u = ul + 32;
      float gi = gates_t[chunk][      u] + gxv[4];
      float gf = gates_t[chunk][ 64 + u] + gxv[5];
      float gg = gates_t[chunk][128 + u] + gxv[6];
      float go = gates_t[chunk][192 + u] + gxv[7];
      float si = 1.f/(1.f + __expf(-gi));
      float sf = 1.f/(1.f + __expf(-gf));
      float tg = 1.f - 2.f/(1.f + __expf(2.f*gg));
      c1 = sf*c1 + si*tg;
      float th = 1.f - 2.f/(1.f + __expf(2.f*c1));
      hv1 = (1.f/(1.f + __expf(-go))) * th;
    }
    u16 hb0 = f2bf(hv0), hb1 = f2bf(hv1);
    h_bf[par^1][chunk][blk*64 + ul     ] = hb0;
    h_bf[par^1][chunk][blk*64 + ul + 32] = hb1;
    // tagged publish: one 8B relaxed agent atomic carries data + validity
    unsigned want = (unsigned)(sl + 1);
    {
      unsigned pk32 = (unsigned)hb0 | ((unsigned)hb1 << 16);
      u64 pk = (u64)pk32 | ((u64)want << 32);
      __hip_atomic_store(&pub_t[par*(TPB_TEAM*512) + blk*512 + t], pk,
                         __ATOMIC_RELAXED, __HIP_MEMORY_SCOPE_AGENT);
    }
    if (s >= cstart && s < cend){
      hout[(size_t)s*HID + blk*64 + ul     ] = hb0;
      hout[(size_t)s*HID + blk*64 + ul + 32] = hb1;
    }
    // ---- parallel wait-all poll: all 4 loads in flight per retry round ----
    {
      const u64* base = (const u64*)((const char*)0);
      (void)base;
      u64 v[4];
      const u64* p0 = rp[0] + par*(TPB_TEAM*512);
      const u64* p1 = rp[1] + par*(TPB_TEAM*512);
      const u64* p2 = rp[2] + par*(TPB_TEAM*512);
      const u64* p3 = rp[3] + par*(TPB_TEAM*512);
      v[0] = __hip_atomic_load(p0, __ATOMIC_RELAXED, __HIP_MEMORY_SCOPE_AGENT);
      v[1] = __hip_atomic_load(p1, __ATOMIC_RELAXED, __HIP_MEMORY_SCOPE_AGENT);
      v[2] = __hip_atomic_load(p2, __ATOMIC_RELAXED, __HIP_MEMORY_SCOPE_AGENT);
      v[3] = __hip_atomic_load(p3, __ATOMIC_RELAXED, __HIP_MEMORY_SCOPE_AGENT);
      while (((unsigned)(v[0] >> 32) != want) | ((unsigned)(v[1] >> 32) != want) |
             ((unsigned)(v[2] >> 32) != want) | ((unsigned)(v[3] >> 32) != want)){
        if ((unsigned)(v[0] >> 32) != want)
          v[0] = __hip_atomic_load(p0, __ATOMIC_RELAXED, __HIP_MEMORY_SCOPE_AGENT);
        if ((unsigned)(v[1] >> 32) != want)
          v[1] = __hip_atomic_load(p1, __ATOMIC_RELAXED, __HIP_MEMORY_SCOPE_AGENT);
        if ((unsigned)(v[2] >> 32) != want)
          v[2] = __hip_atomic_load(p2, __ATOMIC_RELAXED, __HIP_MEMORY_SCOPE_AGENT);
        if ((unsigned)(v[3] >> 32) != want)
          v[3] = __hip_atomic_load(p3, __ATOMIC_RELAXED, __HIP_MEMORY_SCOPE_AGENT);
      }
      #pragma unroll
      for (int j = 0; j < 4; ++j){
        int rb = j + (j >= blk);
        unsigned pk2 = (unsigned)v[j];
        h_bf[par^1][chunk][rb*64 + ul     ] = (u16)(pk2 & 0xFFFFu);
        h_bf[par^1][chunk][rb*64 + ul + 32] = (u16)(pk2 >> 16);
      }
    }
    __syncthreads();
  }
}

// ---------------- GCN: CSR build (counting sort by dst) + gather ----------------
__global__ void k_hist(const int* __restrict__ ei, int* deg){
  int e = blockIdx.x*256 + threadIdx.x;
  if (e < NE) atomicAdd(&deg[ei[NE + e]], 1);
}

__global__ void k_offsets(const int* __restrict__ deg, int* off, int* cursor){
  __shared__ int sdata[1024];
  int t = threadIdx.x;
  int loc[8]; int s = 0;
  #pragma unroll
  for (int j = 0; j < 8; j++){ loc[j] = deg[t*8 + j]; s += loc[j]; }
  sdata[t] = s; __syncthreads();
  for (int d = 1; d < 1024; d <<= 1){
    int add = (t >= d) ? sdata[t-d] : 0;
    __syncthreads();
    sdata[t] += add;
    __syncthreads();
  }
  int run = sdata[t] - s;
  #pragma unroll
  for (int j = 0; j < 8; j++){ off[t*8+j] = run; cursor[t*8+j] = run; run += loc[j]; }
  if (t == 1023) off[NN] = run;
}

__global__ void k_scatter(const int* __restrict__ ei, const float* __restrict__ ew,
                          int* cursor, int* esrc, float* ews){
  int e = blockIdx.x*256 + threadIdx.x;
  if (e < NE){
    int d = ei[NE + e];
    int p = atomicAdd(&cursor[d], 1);
    esrc[p] = ei[e];
    ews[p] = ew[e];
  }
}

// one wave per dst node; XW packed-bf16 (F2 u32/row). Output packed-bf16 or fp32.
__global__ void k_gather(const u16* __restrict__ XWb, int F2,
    const int* __restrict__ off, const int* __restrict__ esrc, const float* __restrict__ ews,
    const float* __restrict__ bias, u16* outb, float* outf, int ld2, int Fo, int lrFlag)
{
  int node = blockIdx.x*4 + (threadIdx.x >> 6);
  int lane = threadIdx.x & 63;
  const unsigned* XW2 = (const unsigned*)XWb;
  float2 acc[3];
  #pragma unroll
  for (int j = 0; j < 3; ++j) acc[j] = (float2){0.f, 0.f};
  int e0 = off[node], e1 = off[node+1];
  for (int e = e0; e < e1; ++e){
    int sN = esrc[e]; float we = ews[e];
    const unsigned* xr = XW2 + (size_t)sN*F2;
    #pragma unroll
    for (int j = 0; j < 3; ++j){
      int i = j*64 + lane;
      if (i < F2){
        unsigned u = xr[i];
        acc[j].x += we * bf2f((u16)(u & 0xFFFFu));
        acc[j].y += we * bf2f((u16)(u >> 16));
      }
    }
  }
  #pragma unroll
  for (int j = 0; j < 3; ++j){
    int i = j*64 + lane;
    if (i < F2){
      float v0 = acc[j].x + bias[2*i];
      float v1 = acc[j].y + bias[2*i+1];
      if (lrFlag){ v0 = lrelu(v0); v1 = lrelu(v1); }
      if (outb){
        unsigned pk = (unsigned)f2bf(v0) | ((unsigned)f2bf(v1) << 16);
        ((unsigned*)outb)[(size_t)node*ld2 + i] = pk;
      } else {
        outf[(size_t)node*Fo + 2*i    ] = v0;
        outf[(size_t)node*Fo + 2*i + 1] = v1;
      }
    }
  }
  if (outb){
    for (int i = F2 + lane; i < ld2; i += 64)
      ((unsigned*)outb)[(size_t)node*ld2 + i] = 0u;
  }
}

// ---------------- BN stats + fused BN/pool/FC ----------------
__global__ void k_bnstats(const float* __restrict__ conv4, float* mu, float* iv){
  int f = blockIdx.x, t = threadIdx.x;
  float s = 0, ss = 0;
  for (int i = t; i < NN; i += 256){ float v = conv4[(size_t)i*50 + f]; s += v; ss += v*v; }
  __shared__ float S[256], SS[256];
  S[t] = s; SS[t] = ss; __syncthreads();
  for (int d = 128; d > 0; d >>= 1){ if (t < d){ S[t] += S[t+d]; SS[t] += SS[t+d]; } __syncthreads(); }
  if (t == 0){
    float m = S[0] / (float)NN;
    float var = SS[0] / (float)NN - m*m;
    mu[f] = m; iv[f] = rsqrtf(var + 1e-5f);
  }
}

__global__ void k_final(const float* __restrict__ conv4, const float* __restrict__ mu,
    const float* __restrict__ iv, const float* __restrict__ gamma, const float* __restrict__ beta,
    const float* __restrict__ f1W, const float* __restrict__ f1b,
    const float* __restrict__ f2W, const float* __restrict__ f2b,
    const float* __restrict__ f3W, const float* __restrict__ f3b, float* __restrict__ out)
{
  int g = blockIdx.x, t = threadIdx.x;
  __shared__ float pl[50]; __shared__ float o1[30]; __shared__ float o2[20];
  if (t < 50){
    float mf = mu[t], ivf = iv[t], ga = gamma[t], be = beta[t];
    float s = 0;
    for (int i = 0; i < 8; i++){
      float v = conv4[(size_t)(g*8+i)*50 + t];
      v = ga*(v - mf)*ivf + be;
      s += lrelu(v);
    }
    pl[t] = s;
  }
  __syncthreads();
  if (t < 30){ float a = f1b[t]; for (int f = 0; f < 50; f++) a += pl[f]*f1W[f*30+t]; o1[t] = lrelu(a); }
  __syncthreads();
  if (t < 20){ float a = f2b[t]; for (int j = 0; j < 30; j++) a += o1[j]*f2W[j*20+t]; o2[t] = lrelu(a); }
  __syncthreads();
  if (t < 2){  float a = f3b[t]; for (int j = 0; j < 20; j++) a += o2[j]*f3W[j*2+t]; out[g*2+t] = lrelu(a); }
}

// ---------------- host ----------------
extern "C" void kernel_launch(void* const* d_in, const int* in_sizes, int n_in,
                              void* d_out, int out_size, void* d_ws, size_t ws_size,
                              hipStream_t stream) {
  const float* x    = (const float*)d_in[0];
  const int*   ei   = (const int*)  d_in[1];
  const float* ew   = (const float*)d_in[2];
  const float* Wih0 = (const float*)d_in[4];
  const float* Whh0 = (const float*)d_in[5];
  const float* bi0  = (const float*)d_in[6];
  const float* bh0  = (const float*)d_in[7];
  const float* Wih1 = (const float*)d_in[8];
  const float* Whh1 = (const float*)d_in[9];
  const float* bi1  = (const float*)d_in[10];
  const float* bh1  = (const float*)d_in[11];
  const float* Wg1  = (const float*)d_in[12];
  const float* bg1  = (const float*)d_in[13];
  const float* Wg2  = (const float*)d_in[14];
  const float* bg2  = (const float*)d_in[15];
  const float* Wg3  = (const float*)d_in[16];
  const float* bg3  = (const float*)d_in[17];
  const float* Wg4  = (const float*)d_in[18];
  const float* bg4  = (const float*)d_in[19];
  const float* gam  = (const float*)d_in[20];
  const float* bet  = (const float*)d_in[21];
  const float* f1W  = (const float*)d_in[22];
  const float* f1b  = (const float*)d_in[23];
  const float* f2W  = (const float*)d_in[24];
  const float* f2b  = (const float*)d_in[25];
  const float* f3W  = (const float*)d_in[26];
  const float* f3b  = (const float*)d_in[27];

  char* ws = (char*)d_ws;
  size_t o = 0;
  auto alloc = [&](size_t bytes)->char*{ char* p = ws + o; o += (bytes + 255) & ~(size_t)255; return p; };
  u16*   gxb   = (u16*)  alloc((size_t)NN*FOUR_H*2);
  u16*   h0b   = (u16*)  alloc((size_t)NN*HID*2);
  u16*   h1b   = (u16*)  alloc((size_t)NN*HID*2);
  u16*   actA  = (u16*)  alloc((size_t)NN*FIN*2);
  u16*   actL  = (u16*)  alloc((size_t)NN*HID*2);
  u16*   g1o   = (u16*)  alloc((size_t)NN*320*2);
  u16*   g2o   = (u16*)  alloc((size_t)NN*192*2);
  u16*   g3o   = (u16*)  alloc((size_t)NN*96*2);
  u16*   XW    = (u16*)  alloc((size_t)NN*320*2);
  float* conv4 = (float*)alloc((size_t)NN*50*4);
  u16*   Wih0b = (u16*)  alloc((size_t)1280*1280*2);
  u16*   Wih1b = (u16*)  alloc((size_t)1280*320*2);
  u16*   Whh0b = (u16*)  alloc((size_t)1280*320*2);
  u16*   Whh1b = (u16*)  alloc((size_t)1280*320*2);
  u16*   W1T   = (u16*)  alloc((size_t)320*320*2);
  u16*   W2T   = (u16*)  alloc((size_t)192*320*2);
  u16*   W3T   = (u16*)  alloc((size_t)128*192*2);
  u16*   W4T   = (u16*)  alloc((size_t)64*96*2);
  float* bs0   = (float*)alloc(1280*4);
  float* bs1   = (float*)alloc(1280*4);
  float* mu    = (float*)alloc(256);
  float* iv    = (float*)alloc(256);
  int*   deg   = (int*)  alloc(NN*4);
  int*   off   = (int*)  alloc((NN+1)*4);
  int*   cursor= (int*)  alloc(NN*4);
  int*   esrc  = (int*)  alloc((size_t)NE*4);
  float* ews   = (float*)alloc((size_t)NE*4);
  u64*   pub0  = (u64*)  alloc((size_t)TEAMS*2*TPB_TEAM*512*8);
  u64*   pub1  = (u64*)  alloc((size_t)TEAMS*2*TPB_TEAM*512*8);
  (void)ws_size; (void)in_sizes; (void)n_in; (void)out_size;

  // prep
  k_zero<<<32, 256, 0, stream>>>(deg);
  k_bias<<<10, 256, 0, stream>>>(bi0, bh0, bi1, bh1, bs0, bs1);
  k_cvt<<<dim3(5, NN),   256, 0, stream>>>(x,    actA,  1280, 1280);
  k_cvt<<<dim3(5, 1280), 256, 0, stream>>>(Wih0, Wih0b, 1280, 1280);
  k_cvt<<<dim3(2, 1280), 256, 0, stream>>>(Wih1, Wih1b, 320,  320);
  k_cvt<<<dim3(2, 1280), 256, 0, stream>>>(Whh0, Whh0b, 320,  320);
  k_cvt<<<dim3(2, 1280), 256, 0, stream>>>(Whh1, Whh1b, 320,  320);
  k_wT<<<dim3(320, 2), 256, 0, stream>>>(Wg1, W1T, 320, 320, 320);
  k_wT<<<dim3(192, 2), 256, 0, stream>>>(Wg2, W2T, 320, 180, 320);
  k_wT<<<dim3(128, 1), 256, 0, stream>>>(Wg3, W3T, 180, 90, 192);
  k_wT<<<dim3(64, 1),  256, 0, stream>>>(Wg4, W4T, 90, 50, 96);
  // CSR build
  k_hist<<<512, 256, 0, stream>>>(ei, deg);
  k_offsets<<<1, 1024, 0, stream>>>(deg, off, cursor);
  k_scatter<<<512, 256, 0, stream>>>(ei, ew, cursor, esrc, ews);

  // LSTM layer 0
  gemm_bt<<<dim3(64, 20), 256, 0, stream>>>(actA, 1280, Wih0b, 1280, gxb, 1280, 1280, 40, bs0);
  {
    const u16* a0 = gxb; const u16* a1 = Whh0b; u16* a2 = h0b; u64* a3 = pub0;
    void* kargs[4] = {&a0, &a1, &a2, &a3};
    if (hipLaunchCooperativeKernel((const void*)lstm_scan, dim3(TEAMS*TPB_TEAM), dim3(512),
                                   kargs, 0, stream) != hipSuccess)
      lstm_scan<<<dim3(TEAMS*TPB_TEAM), 512, 0, stream>>>(a0, a1, a2, a3);
  }
  // LSTM layer 1
  gemm_bt<<<dim3(64, 20), 256, 0, stream>>>(h0b, 320, Wih1b, 320, gxb, 1280, 1280, 10, bs1);
  {
    const u16* a0 = gxb; const u16* a1 = Whh1b; u16* a2 = h1b; u64* a3 = pub1;
    void* kargs[4] = {&a0, &a1, &a2, &a3};
    if (hipLaunchCooperativeKernel((const void*)lstm_scan, dim3(TEAMS*TPB_TEAM), dim3(512),
                                   kargs, 0, stream) != hipSuccess)
      lstm_scan<<<dim3(TEAMS*TPB_TEAM), 512, 0, stream>>>(a0, a1, a2, a3);
  }
  k_lrelu_bf<<<NN*HID/256, 256, 0, stream>>>(h1b, actL);

  // GCN stack
  gemm_bt<<<dim3(64, 5), 256, 0, stream>>>(actL, 320, W1T, 320, XW, 320, 320, 10, nullptr);
  k_gather<<<2048, 256, 0, stream>>>(XW, 160, off, esrc, ews, bg1, g1o, nullptr, 160, 320, 1);
  gemm_bt<<<dim3(64, 3), 256, 0, stream>>>(g1o, 320, W2T, 320, XW, 180, 180, 10, nullptr);
  k_gather<<<2048, 256, 0, stream>>>(XW, 90, off, esrc, ews, bg2, g2o, nullptr, 96, 180, 1);
  gemm_bt<<<dim3(64, 2), 256, 0, stream>>>(g2o, 192, W3T, 192, XW, 90, 90, 6, nullptr);
  k_gather<<<2048, 256, 0, stream>>>(XW, 45, off, esrc, ews, bg3, g3o, nullptr, 48, 90, 1);
  gemm_bt<<<dim3(64, 1), 256, 0, stream>>>(g3o, 96, W4T, 96, XW, 50, 50, 3, nullptr);
  k_gather<<<2048, 256, 0, stream>>>(XW, 25, off, esrc, ews, bg4, nullptr, conv4, 0, 50, 0);

  // BN + pool + FC head
  k_bnstats<<<50, 256, 0, stream>>>(conv4, mu, iv);
  k_final<<<NG, 64, 0, stream>>>(conv4, mu, iv, gam, bet, f1W, f1b, f2W, f2b, f3W, f3b,
                                 (float*)d_out);
}

// Round 7
// 865.229 us; speedup vs baseline: 1.1859x; 1.0297x over previous
//
#include <hip/hip_runtime.h>
#include <cstdint>
#include <cstddef>

// ---------------- problem constants ----------------
#define NN 8192      // nodes (= LSTM sequence length)
#define FIN 1280
#define HID 320
#define FOUR_H 1280
#define NE 131072
#define NG 1024

// ---- chunked-parallel scan decomposition (MFMA-batched) ----
#define TEAMS 51
#define TPB_TEAM 5
#define B_CH 16
#define CHUNK_L 11
#define BURN 40
#define NSTEPS (BURN + CHUNK_L)   // 51
#define HPAD 344                  // bf16 h row stride
#define GPAD 260                  // gates_t row stride (floats)

typedef unsigned short u16;
typedef unsigned long long u64;
typedef __attribute__((ext_vector_type(8))) short bf16x8;     // 4 VGPRs
typedef __attribute__((ext_vector_type(4))) float f32x4;
typedef __attribute__((ext_vector_type(4))) unsigned u32x4;   // ext_vector: legal asm "v" operand

__device__ __forceinline__ float lrelu(float x){ return x > 0.f ? x : 0.01f*x; }
__device__ __forceinline__ u16 f2bf(float f){
  unsigned u = __float_as_uint(f);
  u = (u + 0x7FFFu + ((u >> 16) & 1u)) >> 16;   // RNE
  return (u16)u;
}
__device__ __forceinline__ float bf2f(u16 v){ return __uint_as_float((unsigned)v << 16); }

// 16B L1/L2-bypassing (LLC-coherent) store/load — HIP uint4 is a struct and
// trips "indirect register inputs"; ext_vector u32x4 maps to a VGPR quad.
__device__ __forceinline__ void store16_sc(void* p, u32x4 v){
  asm volatile("global_store_dwordx4 %0, %1, off sc0 sc1"
               :: "v"(p), "v"(v) : "memory");
}
__device__ __forceinline__ u32x4 load16_sc(const void* p){
  u32x4 r;
  asm volatile("global_load_dwordx4 %0, %1, off sc0 sc1"
               : "=v"(r) : "v"(p) : "memory");
  return r;
}

// ---------------- fused prep kernel (was 10 launches) ----------------
#define SEG0 32                 // deg zero
#define SEG1 (SEG0 + 10)        // bias sums
#define SEG2 (SEG1 + 40960)     // x -> bf16
#define SEG3 (SEG2 + 6400)      // Wih0 -> bf16
#define SEG4 (SEG3 + 1600)      // Wih1
#define SEG5 (SEG4 + 1600)      // Whh0
#define SEG6 (SEG5 + 1600)      // Whh1
#define SEG7 (SEG6 + 400)       // W1T 320x320
#define SEG8 (SEG7 + 240)       // W2T 192x320
#define SEG9 (SEG8 + 96)        // W3T 128x192
#define SEGA (SEG9 + 24)        // W4T 64x96

__global__ void k_prep(
    int* deg,
    const float* bi0, const float* bh0, const float* bi1, const float* bh1,
    float* bs0, float* bs1,
    const float* x, u16* actA,
    const float* Wih0, u16* Wih0b,
    const float* Wih1, u16* Wih1b,
    const float* Whh0, u16* Whh0b,
    const float* Whh1, u16* Whh1b,
    const float* Wg1, u16* W1T,
    const float* Wg2, u16* W2T,
    const float* Wg3, u16* W3T,
    const float* Wg4, u16* W4T)
{
  int b = blockIdx.x, t = threadIdx.x;
  if (b < SEG0){ deg[b*256 + t] = 0; return; }
  if (b < SEG1){
    int e = (b - SEG0)*256 + t;
    if (e < 1280) bs0[e] = bi0[e] + bh0[e];
    else if (e < 2560){ int j = e - 1280; bs1[j] = bi1[j] + bh1[j]; }
    return;
  }
  if (b < SEG2){ int e = (b - SEG1)*256 + t; actA [e] = f2bf(x   [e]); return; }
  if (b < SEG3){ int e = (b - SEG2)*256 + t; Wih0b[e] = f2bf(Wih0[e]); return; }
  if (b < SEG4){ int e = (b - SEG3)*256 + t; Wih1b[e] = f2bf(Wih1[e]); return; }
  if (b < SEG5){ int e = (b - SEG4)*256 + t; Whh0b[e] = f2bf(Whh0[e]); return; }
  if (b < SEG6){ int e = (b - SEG5)*256 + t; Whh1b[e] = f2bf(Whh1[e]); return; }
  if (b < SEG7){ int e = (b - SEG6)*256 + t; int n = e/320, k = e%320;
                 W1T[e] = f2bf(Wg1[k*320 + n]); return; }
  if (b < SEG8){ int e = (b - SEG7)*256 + t; int n = e/320, k = e%320;
                 W2T[e] = (n < 180) ? f2bf(Wg2[k*180 + n]) : (u16)0; return; }
  if (b < SEG9){ int e = (b - SEG8)*256 + t; int n = e/192, k = e%192;
                 W3T[e] = (n < 90 && k < 180) ? f2bf(Wg3[k*90 + n]) : (u16)0; return; }
  {            int e = (b - SEG9)*256 + t; int n = e/96,  k = e%96;
                 W4T[e] = (n < 50 && k < 90) ? f2bf(Wg4[k*50 + n]) : (u16)0; return; }
}

// ------- bf16 MFMA GEMM: C[M,N] = A[M,K] * B[N,K]^T + bias, bf16 out -------
__global__ __launch_bounds__(256) void gemm_bt(
    const u16* __restrict__ A, int lda,
    const u16* __restrict__ B, int ldb,
    u16* __restrict__ C, int ldc, int Nn, int kIters,
    const float* __restrict__ bias)
{
  __shared__ __align__(16) u16 As[128][40];
  __shared__ __align__(16) u16 Bs[64][40];
  int t = threadIdx.x; int wv = t >> 6; int ln = t & 63;
  int m0 = blockIdx.x*128, n0 = blockIdx.y*64;
  f32x4 acc[2][4];
  #pragma unroll
  for (int a = 0; a < 2; ++a)
    #pragma unroll
    for (int j = 0; j < 4; ++j) acc[a][j] = (f32x4){0,0,0,0};
  int sr = t >> 2, sc = (t & 3) * 8;
  const u16* Ap0 = A + (size_t)(m0+sr)*lda + sc;
  const u16* Ap1 = A + (size_t)(m0+64+sr)*lda + sc;
  const u16* Bp  = B + (size_t)(n0+sr)*ldb + sc;
  int fr = ln & 15, quad = ln >> 4;
  for (int kt = 0; kt < kIters; ++kt){
    uint4 a0 = *(const uint4*)(Ap0 + kt*32);
    uint4 a1 = *(const uint4*)(Ap1 + kt*32);
    uint4 bv = *(const uint4*)(Bp  + kt*32);
    *(uint4*)(&As[sr][sc])    = a0;
    *(uint4*)(&As[64+sr][sc]) = a1;
    *(uint4*)(&Bs[sr][sc])    = bv;
    __syncthreads();
    bf16x8 afA = *(const bf16x8*)(&As[wv*32 +      fr][quad*8]);
    bf16x8 afB = *(const bf16x8*)(&As[wv*32 + 16 + fr][quad*8]);
    #pragma unroll
    for (int j = 0; j < 4; ++j){
      bf16x8 bf = *(const bf16x8*)(&Bs[j*16 + fr][quad*8]);
      acc[0][j] = __builtin_amdgcn_mfma_f32_16x16x32_bf16(afA, bf, acc[0][j], 0,0,0);
      acc[1][j] = __builtin_amdgcn_mfma_f32_16x16x32_bf16(afB, bf, acc[1][j], 0,0,0);
    }
    __syncthreads();
  }
  #pragma unroll
  for (int a = 0; a < 2; ++a){
    int row0 = m0 + wv*32 + a*16 + quad*4;
    #pragma unroll
    for (int nt = 0; nt < 4; ++nt){
      int col = n0 + nt*16 + fr;
      if (col < Nn){
        float bb = bias ? bias[col] : 0.f;
        #pragma unroll
        for (int i = 0; i < 4; ++i)
          C[(size_t)(row0+i)*ldc + col] = f2bf(acc[a][nt][i] + bb);
      }
    }
  }
}

// ---------------- MFMA-batched chunk-parallel LSTM scan ----------------
// R6/R7: (1) weight frags pinned in VGPRs via opaque asm; (2) 16B sc0/sc1
// wide publish/pull (lane-paired tagged u64s) halves LLC request count;
// (3) gx prefetch after the mid-step barrier overlaps the partner wait.
__global__ __launch_bounds__(512, 2) void lstm_scan(
    const u16* __restrict__ gxb, const u16* __restrict__ Whh_bf,
    u16* __restrict__ hout, u64* pub, int lrFlag)
{
  int b = blockIdx.x;
  int team = b / TPB_TEAM, blk = b % TPB_TEAM;
  int t = threadIdx.x;
  int w = t >> 6, lane = t & 63;
  int fr = lane & 15, quad = lane >> 4;

  // register-resident bf16 B-fragments of W_hh (2 N-tiles x 10 K-frags)
  bf16x8 wf0[10], wf1[10];
  {
    int n0l = w*32 + fr;
    int n1l = w*32 + 16 + fr;
    int g0 = n0l >> 6, u0 = n0l & 63;
    int g1 = n1l >> 6, u1 = n1l & 63;
    const u16* wp0 = Whh_bf + (size_t)(g0*320 + blk*64 + u0)*320 + quad*8;
    const u16* wp1 = Whh_bf + (size_t)(g1*320 + blk*64 + u1)*320 + quad*8;
    #pragma unroll
    for (int kt = 0; kt < 10; ++kt){
      wf0[kt] = *(const bf16x8*)(wp0 + kt*32);
      wf1[kt] = *(const bf16x8*)(wp1 + kt*32);
    }
    #pragma unroll
    for (int kt = 0; kt < 10; ++kt){
      asm volatile("" : "+v"(wf0[kt]));
      asm volatile("" : "+v"(wf1[kt]));
    }
  }

  __shared__ __align__(16) u16 h_bf[2][B_CH][HPAD];     // bf16 h, A-frag layout
  __shared__ __align__(16) float gates_t[B_CH][GPAD];   // [chunk][n_local]
  for (int i = t; i < 2*B_CH*HPAD; i += 512) ((u16*)h_bf)[i] = 0;

  int chunk = t >> 5;
  int ul = t & 31;
  int cid = team*B_CH + chunk;
  int cstart = cid * CHUNK_L;
  int cend = min(NN, cstart + CHUNK_L);
  float c0 = 0.f, c1 = 0.f;
  u64* pub_t = pub + (size_t)team * (2*TPB_TEAM*512);

  // consumer mapping: thread t pulls 16B slot-pairs (2q,2q+1) of 2 partners
  int q = t & 255;
  int j2 = t >> 8;                 // 0/1
  int jB = j2 + 2;
  int rbA = j2 + (j2 >= blk);
  int rbB = jB + (jB >= blk);
  int cch = (2*q) >> 5;            // chunk of consumed slots
  int cul = (2*q) & 31;            // even, <= 30

  // initial one-step-ahead gx prefetch (bf16)
  float gxn[8];
  {
    int s = cstart - BURN;
    bool sv = (s >= 0) && (s < NN);
    #pragma unroll
    for (int r = 0; r < 2; ++r)
      #pragma unroll
      for (int g = 0; g < 4; ++g)
        gxn[r*4+g] = sv ? bf2f(gxb[(size_t)s*FOUR_H + g*320 + blk*64 + ul + 32*r]) : 0.f;
  }
  __syncthreads();

  for (int sl = 0; sl < NSTEPS; ++sl){
    int par = sl & 1;
    int s = cstart - BURN + sl;
    float gxv[8];
    #pragma unroll
    for (int i = 0; i < 8; ++i) gxv[i] = gxn[i];

    // batched matvec: gates[16 chunks][256 rows] = h x W^T
    f32x4 acc0 = {0,0,0,0}, acc1 = {0,0,0,0};
    #pragma unroll
    for (int kt = 0; kt < 10; ++kt){
      bf16x8 a = *(const bf16x8*)(&h_bf[par][fr][kt*32 + quad*8]);
      acc0 = __builtin_amdgcn_mfma_f32_16x16x32_bf16(a, wf0[kt], acc0, 0, 0, 0);
      acc1 = __builtin_amdgcn_mfma_f32_16x16x32_bf16(a, wf1[kt], acc1, 0, 0, 0);
    }
    #pragma unroll
    for (int i = 0; i < 4; ++i){
      gates_t[quad*4+i][w*32 +      fr] = acc0[i];
      gates_t[quad*4+i][w*32 + 16 + fr] = acc1[i];
    }
    __syncthreads();

    // prefetch gx for sl+1 — wait folds into the poll's vmcnt(0)
    {
      int sn = s + 1;
      bool sv = (sl+1 < NSTEPS) && (sn >= 0) && (sn < NN);
      #pragma unroll
      for (int r = 0; r < 2; ++r)
        #pragma unroll
        for (int g = 0; g < 4; ++g)
          gxn[r*4+g] = sv ? bf2f(gxb[(size_t)sn*FOUR_H + g*320 + blk*64 + ul + 32*r]) : 0.f;
    }

    float hv0, hv1;
    {
      int u = ul;
      float gi = gates_t[chunk][      u] + gxv[0];
      float gf = gates_t[chunk][ 64 + u] + gxv[1];
      float gg = gates_t[chunk][128 + u] + gxv[2];
      float go = gates_t[chunk][192 + u] + gxv[3];
      float si = 1.f/(1.f + __expf(-gi));
      float sf = 1.f/(1.f + __expf(-gf));
      float tg = 1.f - 2.f/(1.f + __expf(2.f*gg));
      c0 = sf*c0 + si*tg;
      float th = 1.f - 2.f/(1.f + __expf(2.f*c0));
      hv0 = (1.f/(1.f + __expf(-go))) * th;
    }
    {
      int u = ul + 32;
      float gi = gates_t[chunk][      u] + gxv[4];
      float gf = gates_t[chunk][ 64 + u] + gxv[5];
      float gg = gates_t[chunk][128 + u] + gxv[6];
      float go = gates_t[chunk][192 + u] + gxv[7];
      float si = 1.f/(1.f + __expf(-gi));
      float sf = 1.f/(1.f + __expf(-gf));
      float tg = 1.f - 2.f/(1.f + __expf(2.f*gg));
      c1 = sf*c1 + si*tg;
      float th = 1.f - 2.f/(1.f + __expf(2.f*c1));
      hv1 = (1.f/(1.f + __expf(-go))) * th;
    }
    u16 hb0 = f2bf(hv0), hb1 = f2bf(hv1);
    h_bf[par^1][chunk][blk*64 + ul     ] = hb0;
    h_bf[par^1][chunk][blk*64 + ul + 32] = hb1;

    unsigned want = (unsigned)(sl + 1);
    // lane-paired 16B tagged publish (even lanes store {mine, lane+1's})
    {
      unsigned pk32 = (unsigned)hb0 | ((unsigned)hb1 << 16);
      u64 pk = (u64)pk32 | ((u64)want << 32);
      u64 pk1 = __shfl_down(pk, 1, 64);
      if (!(lane & 1)){
        u32x4 val;
        val.x = (unsigned)pk;  val.y = (unsigned)(pk  >> 32);
        val.z = (unsigned)pk1; val.w = (unsigned)(pk1 >> 32);
        store16_sc(pub_t + par*(TPB_TEAM*512) + blk*512 + t, val);
      }
    }
    if (s >= cstart && s < cend){
      u16 o0 = hb0, o1 = hb1;
      if (lrFlag){ o0 = f2bf(lrelu(hv0)); o1 = f2bf(lrelu(hv1)); }
      hout[(size_t)s*HID + blk*64 + ul     ] = o0;
      hout[(size_t)s*HID + blk*64 + ul + 32] = o1;
    }
    // 16B wide poll: 2 partner slot-pairs per thread, tags in both halves
    {
      u64* baseP = pub_t + par*(TPB_TEAM*512);
      const void* aA = (const void*)(baseP + rbA*512 + 2*q);
      const void* aB = (const void*)(baseP + rbB*512 + 2*q);
      u32x4 vA = load16_sc(aA);
      u32x4 vB = load16_sc(aB);
      asm volatile("s_waitcnt vmcnt(0)" ::: "memory");
      while (((vA.y != want) | (vA.w != want) | (vB.y != want) | (vB.w != want))){
        __builtin_amdgcn_s_sleep(1);
        if ((vA.y != want) | (vA.w != want)) vA = load16_sc(aA);
        if ((vB.y != want) | (vB.w != want)) vB = load16_sc(aB);
        asm volatile("s_waitcnt vmcnt(0)" ::: "memory");
      }
      // slot 2q: lo16=h[cul], hi16=h[cul+32]; slot 2q+1: h[cul+1], h[cul+33]
      unsigned loA = (vA.x & 0xFFFFu) | (vA.z << 16);
      unsigned hiA = (vA.x >> 16)     | (vA.z & 0xFFFF0000u);
      unsigned loB = (vB.x & 0xFFFFu) | (vB.z << 16);
      unsigned hiB = (vB.x >> 16)     | (vB.z & 0xFFFF0000u);
      *(unsigned*)&h_bf[par^1][cch][rbA*64 + cul     ] = loA;
      *(unsigned*)&h_bf[par^1][cch][rbA*64 + cul + 32] = hiA;
      *(unsigned*)&h_bf[par^1][cch][rbB*64 + cul     ] = loB;
      *(unsigned*)&h_bf[par^1][cch][rbB*64 + cul + 32] = hiB;
    }
    __syncthreads();
  }
}

// ---------------- GCN: CSR build (counting sort by dst) + gather ----------------
__global__ void k_hist(const int* __restrict__ ei, int* deg){
  int e = blockIdx.x*256 + threadIdx.x;
  if (e < NE) atomicAdd(&deg[ei[NE + e]], 1);
}

__global__ void k_offsets(const int* __restrict__ deg, int* off, int* cursor){
  __shared__ int sdata[1024];
  int t = threadIdx.x;
  int loc[8]; int s = 0;
  #pragma unroll
  for (int j = 0; j < 8; j++){ loc[j] = deg[t*8 + j]; s += loc[j]; }
  sdata[t] = s; __syncthreads();
  for (int d = 1; d < 1024; d <<= 1){
    int add = (t >= d) ? sdata[t-d] : 0;
    __syncthreads();
    sdata[t] += add;
    __syncthreads();
  }
  int run = sdata[t] - s;
  #pragma unroll
  for (int j = 0; j < 8; j++){ off[t*8+j] = run; cursor[t*8+j] = run; run += loc[j]; }
  if (t == 1023) off[NN] = run;
}

__global__ void k_scatter(const int* __restrict__ ei, const float* __restrict__ ew,
                          int* cursor, int* esrc, float* ews){
  int e = blockIdx.x*256 + threadIdx.x;
  if (e < NE){
    int d = ei[NE + e];
    int p = atomicAdd(&cursor[d], 1);
    esrc[p] = ei[e];
    ews[p] = ew[e];
  }
}

// one wave per dst node; XW packed-bf16 (F2 u32/row). Output packed-bf16 or fp32.
__global__ void k_gather(const u16* __restrict__ XWb, int F2,
    const int* __restrict__ off, const int* __restrict__ esrc, const float* __restrict__ ews,
    const float* __restrict__ bias, u16* outb, float* outf, int ld2, int Fo, int lrFlag)
{
  int node = blockIdx.x*4 + (threadIdx.x >> 6);
  int lane = threadIdx.x & 63;
  const unsigned* XW2 = (const unsigned*)XWb;
  float2 acc[3];
  #pragma unroll
  for (int j = 0; j < 3; ++j) acc[j] = (float2){0.f, 0.f};
  int e0 = off[node], e1 = off[node+1];
  for (int e = e0; e < e1; ++e){
    int sN = esrc[e]; float we = ews[e];
    const unsigned* xr = XW2 + (size_t)sN*F2;
    #pragma unroll
    for (int j = 0; j < 3; ++j){
      int i = j*64 + lane;
      if (i < F2){
        unsigned u = xr[i];
        acc[j].x += we * bf2f((u16)(u & 0xFFFFu));
        acc[j].y += we * bf2f((u16)(u >> 16));
      }
    }
  }
  #pragma unroll
  for (int j = 0; j < 3; ++j){
    int i = j*64 + lane;
    if (i < F2){
      float v0 = acc[j].x + bias[2*i];
      float v1 = acc[j].y + bias[2*i+1];
      if (lrFlag){ v0 = lrelu(v0); v1 = lrelu(v1); }
      if (outb){
        unsigned pk = (unsigned)f2bf(v0) | ((unsigned)f2bf(v1) << 16);
        ((unsigned*)outb)[(size_t)node*ld2 + i] = pk;
      } else {
        outf[(size_t)node*Fo + 2*i    ] = v0;
        outf[(size_t)node*Fo + 2*i + 1] = v1;
      }
    }
  }
  if (outb){
    for (int i = F2 + lane; i < ld2; i += 64)
      ((unsigned*)outb)[(size_t)node*ld2 + i] = 0u;
  }
}

// ---------------- BN stats + fused BN/pool/FC ----------------
__global__ void k_bnstats(const float* __restrict__ conv4, float* mu, float* iv){
  int f = blockIdx.x, t = threadIdx.x;
  float s = 0, ss = 0;
  for (int i = t; i < NN; i += 256){ float v = conv4[(size_t)i*50 + f]; s += v; ss += v*v; }
  __shared__ float S[256], SS[256];
  S[t] = s; SS[t] = ss; __syncthreads();
  for (int d = 128; d > 0; d >>= 1){ if (t < d){ S[t] += S[t+d]; SS[t] += SS[t+d]; } __syncthreads(); }
  if (t == 0){
    float m = S[0] / (float)NN;
    float var = SS[0] / (float)NN - m*m;
    mu[f] = m; iv[f] = rsqrtf(var + 1e-5f);
  }
}

__global__ void k_final(const float* __restrict__ conv4, const float* __restrict__ mu,
    const float* __restrict__ iv, const float* __restrict__ gamma, const float* __restrict__ beta,
    const float* __restrict__ f1W, const float* __restrict__ f1b,
    const float* __restrict__ f2W, const float* __restrict__ f2b,
    const float* __restrict__ f3W, const float* __restrict__ f3b, float* __restrict__ out)
{
  int g = blockIdx.x, t = threadIdx.x;
  __shared__ float pl[50]; __shared__ float o1[30]; __shared__ float o2[20];
  if (t < 50){
    float mf = mu[t], ivf = iv[t], ga = gamma[t], be = beta[t];
    float s = 0;
    for (int i = 0; i < 8; i++){
      float v = conv4[(size_t)(g*8+i)*50 + t];
      v = ga*(v - mf)*ivf + be;
      s += lrelu(v);
    }
    pl[t] = s;
  }
  __syncthreads();
  if (t < 30){ float a = f1b[t]; for (int f = 0; f < 50; f++) a += pl[f]*f1W[f*30+t]; o1[t] = lrelu(a); }
  __syncthreads();
  if (t < 20){ float a = f2b[t]; for (int j = 0; j < 30; j++) a += o1[j]*f2W[j*20+t]; o2[t] = lrelu(a); }
  __syncthreads();
  if (t < 2){  float a = f3b[t]; for (int j = 0; j < 20; j++) a += o2[j]*f3W[j*2+t]; out[g*2+t] = lrelu(a); }
}

// ---------------- host ----------------
extern "C" void kernel_launch(void* const* d_in, const int* in_sizes, int n_in,
                              void* d_out, int out_size, void* d_ws, size_t ws_size,
                              hipStream_t stream) {
  const float* x    = (const float*)d_in[0];
  const int*   ei   = (const int*)  d_in[1];
  const float* ew   = (const float*)d_in[2];
  const float* Wih0 = (const float*)d_in[4];
  const float* Whh0 = (const float*)d_in[5];
  const float* bi0  = (const float*)d_in[6];
  const float* bh0  = (const float*)d_in[7];
  const float* Wih1 = (const float*)d_in[8];
  const float* Whh1 = (const float*)d_in[9];
  const float* bi1  = (const float*)d_in[10];
  const float* bh1  = (const float*)d_in[11];
  const float* Wg1  = (const float*)d_in[12];
  const float* bg1  = (const float*)d_in[13];
  const float* Wg2  = (const float*)d_in[14];
  const float* bg2  = (const float*)d_in[15];
  const float* Wg3  = (const float*)d_in[16];
  const float* bg3  = (const float*)d_in[17];
  const float* Wg4  = (const float*)d_in[18];
  const float* bg4  = (const float*)d_in[19];
  const float* gam  = (const float*)d_in[20];
  const float* bet  = (const float*)d_in[21];
  const float* f1W  = (const float*)d_in[22];
  const float* f1b  = (const float*)d_in[23];
  const float* f2W  = (const float*)d_in[24];
  const float* f2b  = (const float*)d_in[25];
  const float* f3W  = (const float*)d_in[26];
  const float* f3b  = (const float*)d_in[27];

  char* ws = (char*)d_ws;
  size_t o = 0;
  auto alloc = [&](size_t bytes)->char*{ char* p = ws + o; o += (bytes + 255) & ~(size_t)255; return p; };
  u16*   gxb   = (u16*)  alloc((size_t)NN*FOUR_H*2);
  u16*   h0b   = (u16*)  alloc((size_t)NN*HID*2);
  u16*   h1b   = (u16*)  alloc((size_t)NN*HID*2);   // scan1 writes lrelu(h1) directly
  u16*   actA  = (u16*)  alloc((size_t)NN*FIN*2);
  u16*   g1o   = (u16*)  alloc((size_t)NN*320*2);
  u16*   g2o   = (u16*)  alloc((size_t)NN*192*2);
  u16*   g3o   = (u16*)  alloc((size_t)NN*96*2);
  u16*   XW    = (u16*)  alloc((size_t)NN*320*2);
  float* conv4 = (float*)alloc((size_t)NN*50*4);
  u16*   Wih0b = (u16*)  alloc((size_t)1280*1280*2);
  u16*   Wih1b = (u16*)  alloc((size_t)1280*320*2);
  u16*   Whh0b = (u16*)  alloc((size_t)1280*320*2);
  u16*   Whh1b = (u16*)  alloc((size_t)1280*320*2);
  u16*   W1T   = (u16*)  alloc((size_t)320*320*2);
  u16*   W2T   = (u16*)  alloc((size_t)192*320*2);
  u16*   W3T   = (u16*)  alloc((size_t)128*192*2);
  u16*   W4T   = (u16*)  alloc((size_t)64*96*2);
  float* bs0   = (float*)alloc(1280*4);
  float* bs1   = (float*)alloc(1280*4);
  float* mu    = (float*)alloc(256);
  float* iv    = (float*)alloc(256);
  int*   deg   = (int*)  alloc(NN*4);
  int*   off   = (int*)  alloc((NN+1)*4);
  int*   cursor= (int*)  alloc(NN*4);
  int*   esrc  = (int*)  alloc((size_t)NE*4);
  float* ews   = (float*)alloc((size_t)NE*4);
  u64*   pub0  = (u64*)  alloc((size_t)TEAMS*2*TPB_TEAM*512*8);
  u64*   pub1  = (u64*)  alloc((size_t)TEAMS*2*TPB_TEAM*512*8);
  (void)ws_size; (void)in_sizes; (void)n_in; (void)out_size;

  // fused prep (zero + bias + all bf16 conversions + GCN weight transposes)
  k_prep<<<SEGA, 256, 0, stream>>>(deg, bi0, bh0, bi1, bh1, bs0, bs1,
                                   x, actA, Wih0, Wih0b, Wih1, Wih1b,
                                   Whh0, Whh0b, Whh1, Whh1b,
                                   Wg1, W1T, Wg2, W2T, Wg3, W3T, Wg4, W4T);
  // CSR build
  k_hist<<<512, 256, 0, stream>>>(ei, deg);
  k_offsets<<<1, 1024, 0, stream>>>(deg, off, cursor);
  k_scatter<<<512, 256, 0, stream>>>(ei, ew, cursor, esrc, ews);

  // LSTM layer 0
  gemm_bt<<<dim3(64, 20), 256, 0, stream>>>(actA, 1280, Wih0b, 1280, gxb, 1280, 1280, 40, bs0);
  {
    const u16* a0 = gxb; const u16* a1 = Whh0b; u16* a2 = h0b; u64* a3 = pub0; int a4 = 0;
    void* kargs[5] = {&a0, &a1, &a2, &a3, &a4};
    if (hipLaunchCooperativeKernel((const void*)lstm_scan, dim3(TEAMS*TPB_TEAM), dim3(512),
                                   kargs, 0, stream) != hipSuccess)
      lstm_scan<<<dim3(TEAMS*TPB_TEAM), 512, 0, stream>>>(a0, a1, a2, a3, a4);
  }
  // LSTM layer 1 (hout gets lrelu applied -> GCN input directly)
  gemm_bt<<<dim3(64, 20), 256, 0, stream>>>(h0b, 320, Wih1b, 320, gxb, 1280, 1280, 10, bs1);
  {
    const u16* a0 = gxb; const u16* a1 = Whh1b; u16* a2 = h1b; u64* a3 = pub1; int a4 = 1;
    void* kargs[5] = {&a0, &a1, &a2, &a3, &a4};
    if (hipLaunchCooperativeKernel((const void*)lstm_scan, dim3(TEAMS*TPB_TEAM), dim3(512),
                                   kargs, 0, stream) != hipSuccess)
      lstm_scan<<<dim3(TEAMS*TPB_TEAM), 512, 0, stream>>>(a0, a1, a2, a3, a4);
  }

  // GCN stack
  gemm_bt<<<dim3(64, 5), 256, 0, stream>>>(h1b, 320, W1T, 320, XW, 320, 320, 10, nullptr);
  k_gather<<<2048, 256, 0, stream>>>(XW, 160, off, esrc, ews, bg1, g1o, nullptr, 160, 320, 1);
  gemm_bt<<<dim3(64, 3), 256, 0, stream>>>(g1o, 320, W2T, 320, XW, 180, 180, 10, nullptr);
  k_gather<<<2048, 256, 0, stream>>>(XW, 90, off, esrc, ews, bg2, g2o, nullptr, 96, 180, 1);
  gemm_bt<<<dim3(64, 2), 256, 0, stream>>>(g2o, 192, W3T, 192, XW, 90, 90, 6, nullptr);
  k_gather<<<2048, 256, 0, stream>>>(XW, 45, off, esrc, ews, bg3, g3o, nullptr, 48, 90, 1);
  gemm_bt<<<dim3(64, 1), 256, 0, stream>>>(g3o, 96, W4T, 96, XW, 50, 50, 3, nullptr);
  k_gather<<<2048, 256, 0, stream>>>(XW, 25, off, esrc, ews, bg4, nullptr, conv4, 0, 50, 0);

  // BN + pool + FC head
  k_bnstats<<<50, 256, 0, stream>>>(conv4, mu, iv);
  k_final<<<NG, 64, 0, stream>>>(conv4, mu, iv, gam, bet, f1W, f1b, f2W, f2b, f3W, f3b,
                                 (float*)d_out);
}